// Round 11
// baseline (180.936 us; speedup 1.0000x reference)
//
#include <hip/hip_runtime.h>
#include <hip/hip_fp16.h>
#include <hip/hip_bf16.h>
#include <math.h>

#define NEG_SLOPE 0.2f
#define BN_EPS 1e-5f
#define EPB 4096          // edges per edge-role block (16 iters of 256)
#define NBMAX 1024        // max bins (64 nodes/bin) -> supports n <= 65536

typedef short  bf16x8 __attribute__((ext_vector_type(8)));
typedef float  f32x4  __attribute__((ext_vector_type(4)));

__device__ __forceinline__ float leaky(float v) {
    return v > 0.0f ? v : NEG_SLOPE * v;
}

__device__ __forceinline__ short bfbits(float f) {
    __hip_bfloat16 h = __float2bfloat16(f);
    return __builtin_bit_cast(short, h);
}

__device__ __forceinline__ bf16x8 cvt8(const float* p) {
    float4 u = *(const float4*)p;
    float4 v = *(const float4*)(p + 4);
    bf16x8 a;
    a[0] = bfbits(u.x); a[1] = bfbits(u.y); a[2] = bfbits(u.z); a[3] = bfbits(u.w);
    a[4] = bfbits(v.x); a[5] = bfbits(v.y); a[6] = bfbits(v.z); a[7] = bfbits(v.w);
    return a;
}

// LDS union: gemm role uses wl (32KB bf16 weights); edge role uses e.*
// (hist 4KB + gbase 4KB + sorted 16KB = 24KB). 32KB total -> 4 blocks/CU.
union SharedU {
    short wl[16384];
    struct { int hist[NBMAX]; int gbase[NBMAX]; int sorted[EPB]; } e;
};

// ======== k_fused: edge counting-sort + MFMA GEMM as block roles ============
// R9 PROVEN: fused ~= max(edge, gemm), not sum (-14us vs sequential). The
// counting-sort edge path is LDS/atomic-heavy with light VMEM, complementary
// to the gemm role's VMEM+MFMA+ds_read. 4 gemm : 1 edge interleave.
// UNCHANGED (control).
__global__ __launch_bounds__(256) void k_fused(
    const float* __restrict__ x, const float* __restrict__ w,
    __half2* __restrict__ h2, const float* __restrict__ att_s,
    const float* __restrict__ att_d, float* __restrict__ a_src,
    float* __restrict__ a_dst, int* __restrict__ bincnt,
    int* __restrict__ binbuf, const int* __restrict__ esrc,
    const int* __restrict__ edst, int n, int E, int gb, int eb)
{
    __shared__ SharedU sh;
    const int tid = threadIdx.x;
    const int q = blockIdx.x / 5;
    const int r = blockIdx.x % 5;

    if (r == 4) {
        // ---- edge role: per-block LDS counting sort, coalesced binned out ---
        const int blk = q;
        if (blk >= eb) return;
        const int e0 = blk * EPB;
        const int ecnt = min(EPB, E - e0);
        int* hist = sh.e.hist;
        int* gbase = sh.e.gbase;
        int* sorted = sh.e.sorted;
        __shared__ int wsum[4];

        for (int i = tid; i < NBMAX; i += 256) hist[i] = 0;
        __syncthreads();

        for (int i = tid; i < ecnt; i += 256)
            atomicAdd(&hist[(unsigned)edst[e0 + i] >> 6], 1);
        __syncthreads();

        // exclusive prefix over NBMAX bins; thread t owns bins 4t..4t+3
        int4 hh = ((int4*)hist)[tid];
        int tot = hh.x + hh.y + hh.z + hh.w;
        int sc = tot;
        const int lane = tid & 63;
        const int wv = tid >> 6;
        #pragma unroll
        for (int off = 1; off < 64; off <<= 1) {
            int v = __shfl_up(sc, off, 64);
            if (lane >= off) sc += v;
        }
        if (lane == 63) wsum[wv] = sc;
        __syncthreads();
        int base = sc - tot;                    // wave-exclusive
        #pragma unroll
        for (int w_ = 0; w_ < 4; ++w_) if (w_ < wv) base += wsum[w_];

        int l0 = base, l1 = l0 + hh.x, l2 = l1 + hh.y, l3 = l2 + hh.z;
        if (hh.x > 0) gbase[4 * tid + 0] =
            ((4 * tid + 0) << 12) + atomicAdd(&bincnt[(4 * tid + 0) * 16], hh.x) - l0;
        if (hh.y > 0) gbase[4 * tid + 1] =
            ((4 * tid + 1) << 12) + atomicAdd(&bincnt[(4 * tid + 1) * 16], hh.y) - l1;
        if (hh.z > 0) gbase[4 * tid + 2] =
            ((4 * tid + 2) << 12) + atomicAdd(&bincnt[(4 * tid + 2) * 16], hh.z) - l2;
        if (hh.w > 0) gbase[4 * tid + 3] =
            ((4 * tid + 3) << 12) + atomicAdd(&bincnt[(4 * tid + 3) * 16], hh.w) - l3;
        __syncthreads();
        hist[4 * tid + 0] = l0;                 // cursor init = local base
        hist[4 * tid + 1] = l1;
        hist[4 * tid + 2] = l2;
        hist[4 * tid + 3] = l3;
        __syncthreads();

        // scatter into LDS-sorted order (LDS atomics: per-CU, cheap)
        for (int i = tid; i < ecnt; i += 256) {
            int s = esrc[e0 + i];
            int d = edst[e0 + i];
            int pos = atomicAdd(&hist[(unsigned)d >> 6], 1);
            sorted[pos] = s | (d << 16);
        }
        __syncthreads();

        // write out: runs contiguous in LDS and global -> coalesced
        for (int i = tid; i < ecnt; i += 256) {
            int rec = sorted[i];
            unsigned bin = (unsigned)rec >> 22;
            int dest = gbase[bin] + i;
            if (dest < (int)((bin + 1) << 12))  // overflow guard (never fires)
                binbuf[dest] = rec;
        }
        return;
    }

    // ---- gemm role: one wave = 16 rows x 128 cols, w staged bf16 in LDS ----
    const int bb = q * 4 + r;
    if (bb >= gb) return;
    short* wl = sh.wl;

    for (int f = tid; f < 2048; f += 256) {
        int m_   = f & 15;
        int g_   = (f >> 4) & 7;
        int q_   = (f >> 7) & 3;
        int k0_  = f >> 9;
        bf16x8 v = cvt8(&w[(size_t)(16 * g_ + m_) * 128 + k0_ * 32 + q_ * 8]);
        *(bf16x8*)&wl[f * 8] = v;
    }
    __syncthreads();

    const int wave = tid >> 6;
    const int lane = tid & 63;
    const int m = lane & 15;
    const int quad = lane >> 4;
    const int r0w = bb * 64 + wave * 16;

    f32x4 acc[8];
    #pragma unroll
    for (int g = 0; g < 8; ++g) acc[g] = (f32x4){0.f, 0.f, 0.f, 0.f};

    const int arow = min(r0w + m, n - 1);
    const float* xrow = x + (size_t)arow * 128 + quad * 8;

    #pragma unroll
    for (int k0 = 0; k0 < 4; ++k0) {
        bf16x8 a = cvt8(xrow + k0 * 32);
        #pragma unroll
        for (int g = 0; g < 8; ++g) {
            bf16x8 b = *(const bf16x8*)&wl[(((k0 * 4 + quad) * 8 + g) * 16 + m) * 8];
            acc[g] = __builtin_amdgcn_mfma_f32_16x16x32_bf16(a, b, acc[g], 0, 0, 0);
        }
    }

    float asv[8], adv[8];
    #pragma unroll
    for (int g = 0; g < 8; ++g) {
        asv[g] = att_s[16 * g + m];
        adv[g] = att_d[16 * g + m];
    }
    float ss[4][4], sd[4][4];          // [reg][head]
    #pragma unroll
    for (int reg = 0; reg < 4; ++reg) {
        #pragma unroll
        for (int h = 0; h < 4; ++h) {
            float ps = acc[2 * h][reg] * asv[2 * h] + acc[2 * h + 1][reg] * asv[2 * h + 1];
            float pd = acc[2 * h][reg] * adv[2 * h] + acc[2 * h + 1][reg] * adv[2 * h + 1];
            #pragma unroll
            for (int msk = 1; msk <= 8; msk <<= 1) {
                ps += __shfl_xor(ps, msk, 64);
                pd += __shfl_xor(pd, msk, 64);
            }
            ss[reg][h] = ps; sd[reg][h] = pd;
        }
    }
    if (m == 0) {
        #pragma unroll
        for (int reg = 0; reg < 4; ++reg) {
            int grow = r0w + quad * 4 + reg;
            if (grow < n) {
                ((float4*)a_src)[grow] = make_float4(ss[reg][0], ss[reg][1], ss[reg][2], ss[reg][3]);
                ((float4*)a_dst)[grow] = make_float4(sd[reg][0], sd[reg][1], sd[reg][2], sd[reg][3]);
            }
        }
    }

    #pragma unroll
    for (int reg = 0; reg < 4; ++reg) {
        int grow = r0w + quad * 4 + reg;
        #pragma unroll
        for (int g = 0; g < 8; ++g) {
            float v0 = acc[g][reg];
            float v1 = __shfl_xor(v0, 1, 64);
            if (!(m & 1) && grow < n)
                h2[(size_t)grow * 64 + 8 * g + (m >> 1)] = __floats2half2_rn(v0, v1);
        }
    }
}

// ======== k_node: DUAL-NODE pairing -- 8 gather chains, no pad doubling =====
// R10 counters: 47.6us, 39% occ, 2.76 TB/s -- still latency-bound; Little's
// law shows ~21 lines/CU in flight = 12 waves x 4 chains. R8 proved widening
// a node's slot window doubles padded fetches (46% of nodes degT<=16).
// Dual-node pairing gets 8 chains WITHOUT widening: each wave processes its
// 4 nodes as 2 pairs; per pair the PV loop issues 4 gathers for node A + 4
// for node B per 16-slot step (each node keeps its own window; unified loop
// bound only pads skewed pairs, and pad gathers hit row 0 in L1). Softmax
// A/B interleaved = 2 a_src chains; out-writes use all 4 lane-groups
// (g=0,1 -> A halves; g=2,3 -> B halves). Across-pair prefetch retained.
// salpha now [4][2][4][72] (~9KB); same per-head stride 72 -> same
// conflict-free bank pattern. All shfl sites: all 64 lanes active.
__global__ __launch_bounds__(256) void k_node(
    const int* __restrict__ bincnt, const int* __restrict__ binbuf,
    const float* __restrict__ a_src, const float* __restrict__ a_dst,
    const __half2* __restrict__ h2, const float* __restrict__ bias,
    float* __restrict__ out, float* __restrict__ pbuf, int n)
{
    __shared__ unsigned short slotsrc[16 * 64];
    __shared__ int cnt2[16];
    __shared__ float salpha[4][2][4][72];
    __shared__ float pb[4][256];
    const int bin = blockIdx.x >> 2;
    const int qsub = blockIdx.x & 3;
    const int tid = threadIdx.x;

    if (tid < 16) cnt2[tid] = 0;
    __syncthreads();

    const int cnt = min(bincnt[bin * 16], 4096);
    const int* bb = binbuf + (size_t)bin * 4096;
    for (int i = tid; i < cnt; i += 256) {
        int e = bb[i];
        int d6 = (e >> 16) & 63;
        if ((d6 >> 4) == qsub) {
            int o = atomicAdd(&cnt2[d6 & 15], 1);
            if (o < 63) slotsrc[(d6 & 15) * 64 + o] = (unsigned short)e;
        }
    }
    __syncthreads();

    const int wv = tid >> 6;
    const int lane = tid & 63;
    const int g  = lane >> 4;
    const int c4 = lane & 15;
    const int head = c4 >> 2;
    const float* apA = &salpha[wv][0][head][0];
    const float* apB = &salpha[wv][1][head][0];
    const float4* h4 = (const float4*)h2;
    const float4* as4 = (const float4*)a_src;
    const float4* ad4 = (const float4*)a_dst;
    const float4 b0 = ((const float4*)bias)[2 * c4];
    const float4 b1 = ((const float4*)bias)[2 * c4 + 1];

    float s8[8], q8[8];
    #pragma unroll
    for (int j = 0; j < 8; ++j) { s8[j] = 0.f; q8[j] = 0.f; }

    // ---- prologue: prefetch pair 0 (nodes wv*4, wv*4+1) ----
    int dlA_n = wv * 4, dlB_n = wv * 4 + 1;
    int dA_n = bin * 64 + qsub * 16 + dlA_n;
    int dB_n = dA_n + 1;
    int degA_n = min(cnt2[dlA_n], 63);
    int degB_n = min(cnt2[dlB_n], 63);
    int mySA_n = 0, mySB_n = 0;
    float4 asA_n = make_float4(0.f, 0.f, 0.f, 0.f);
    float4 asB_n = make_float4(0.f, 0.f, 0.f, 0.f);
    if (lane < degA_n + 1) {
        mySA_n = (lane < degA_n) ? (int)slotsrc[dlA_n * 64 + lane] : dA_n;
        asA_n = as4[mySA_n];               // tail d>=n reads stay inside ws
    }
    if (lane < degB_n + 1) {
        mySB_n = (lane < degB_n) ? (int)slotsrc[dlB_n * 64 + lane] : dB_n;
        asB_n = as4[mySB_n];
    }
    float4 adA_n = ad4[dA_n];
    float4 adB_n = ad4[dB_n];

    for (int it = 0; it < 2; ++it) {
        const int dA = dA_n, dB = dB_n;
        const int degTA = degA_n + 1, degTB = degB_n + 1;
        const int mySA = mySA_n, mySB = mySB_n;
        const float4 asA = asA_n, asB = asB_n;
        const float4 adA = adA_n, adB = adB_n;

        // ---- softmax for A and B, interleaved ----
        float4 exA = make_float4(0.f, 0.f, 0.f, 0.f);
        float4 exB = make_float4(0.f, 0.f, 0.f, 0.f);
        if (lane < degTA)
            exA = make_float4(__expf(leaky(asA.x + adA.x)), __expf(leaky(asA.y + adA.y)),
                              __expf(leaky(asA.z + adA.z)), __expf(leaky(asA.w + adA.w)));
        if (lane < degTB)
            exB = make_float4(__expf(leaky(asB.x + adB.x)), __expf(leaky(asB.y + adB.y)),
                              __expf(leaky(asB.z + adB.z)), __expf(leaky(asB.w + adB.w)));
        float4 smA = exA, smB = exB;
        #pragma unroll
        for (int m = 32; m >= 1; m >>= 1) {
            smA.x += __shfl_xor(smA.x, m, 64); smB.x += __shfl_xor(smB.x, m, 64);
            smA.y += __shfl_xor(smA.y, m, 64); smB.y += __shfl_xor(smB.y, m, 64);
            smA.z += __shfl_xor(smA.z, m, 64); smB.z += __shfl_xor(smB.z, m, 64);
            smA.w += __shfl_xor(smA.w, m, 64); smB.w += __shfl_xor(smB.w, m, 64);
        }
        salpha[wv][0][0][lane] = exA.x / (smA.x + 1e-16f);  // 0 beyond degT
        salpha[wv][0][1][lane] = exA.y / (smA.y + 1e-16f);
        salpha[wv][0][2][lane] = exA.z / (smA.z + 1e-16f);
        salpha[wv][0][3][lane] = exA.w / (smA.w + 1e-16f);
        salpha[wv][1][0][lane] = exB.x / (smB.x + 1e-16f);
        salpha[wv][1][1][lane] = exB.y / (smB.y + 1e-16f);
        salpha[wv][1][2][lane] = exB.z / (smB.z + 1e-16f);
        salpha[wv][1][3][lane] = exB.w / (smB.w + 1e-16f);
        // wave-private LDS: lgkmcnt ordering suffices, no barrier

        // ---- prefetch next pair (round-trip hides under PV loop below) ----
        if (it == 0) {
            dlA_n = wv * 4 + 2; dlB_n = wv * 4 + 3;
            dA_n = bin * 64 + qsub * 16 + dlA_n;
            dB_n = dA_n + 1;
            degA_n = min(cnt2[dlA_n], 63);
            degB_n = min(cnt2[dlB_n], 63);
            mySA_n = 0; mySB_n = 0;
            asA_n = make_float4(0.f, 0.f, 0.f, 0.f);
            asB_n = make_float4(0.f, 0.f, 0.f, 0.f);
            if (lane < degA_n + 1) {
                mySA_n = (lane < degA_n) ? (int)slotsrc[dlA_n * 64 + lane] : dA_n;
                asA_n = as4[mySA_n];
            }
            if (lane < degB_n + 1) {
                mySB_n = (lane < degB_n) ? (int)slotsrc[dlB_n * 64 + lane] : dB_n;
                asB_n = as4[mySB_n];
            }
            adA_n = ad4[dA_n];
            adB_n = ad4[dB_n];
        }

        // ---- PV: unified loop, 8 independent chains (4 per node) ----
        float2 aA0 = {0.f, 0.f}, aA1 = {0.f, 0.f}, aA2 = {0.f, 0.f}, aA3 = {0.f, 0.f};
        float2 aB0 = {0.f, 0.f}, aB1 = {0.f, 0.f}, aB2 = {0.f, 0.f}, aB3 = {0.f, 0.f};
#define ACC4(hv, al, r0, r1, r2, r3)                                         \
        do {                                                                 \
            float2 f0 = __half22float2(__builtin_bit_cast(__half2, hv.x));   \
            float2 f1 = __half22float2(__builtin_bit_cast(__half2, hv.y));   \
            float2 f2 = __half22float2(__builtin_bit_cast(__half2, hv.z));   \
            float2 f3 = __half22float2(__builtin_bit_cast(__half2, hv.w));   \
            r0.x += f0.x * al; r0.y += f0.y * al;                            \
            r1.x += f1.x * al; r1.y += f1.y * al;                            \
            r2.x += f2.x * al; r2.y += f2.y * al;                            \
            r3.x += f3.x * al; r3.y += f3.y * al;                            \
        } while (0)

        const int degMax = max(degTA, degTB);
        for (int kk0 = 0; kk0 < degMax; kk0 += 16) {  // wave-uniform
            int kA = kk0 + g;
            int kB = kk0 + 4 + g;
            int kC = kk0 + 8 + g;
            int kD = kk0 + 12 + g;
            int sA0 = __shfl(mySA, kA, 64);
            int sA1 = __shfl(mySA, kB, 64);
            int sA2 = __shfl(mySA, kC, 64);
            int sA3 = __shfl(mySA, kD, 64);
            int sB0 = __shfl(mySB, kA, 64);
            int sB1 = __shfl(mySB, kB, 64);
            int sB2 = __shfl(mySB, kC, 64);
            int sB3 = __shfl(mySB, kD, 64);
            float lA0 = apA[kA];                    // 0 for k >= degT
            float lA1 = apA[kB];
            float lA2 = apA[kC];
            float lA3 = apA[kD];
            float lB0 = apB[kA];
            float lB1 = apB[kB];
            float lB2 = apB[kC];
            float lB3 = apB[kD];
            float4 hA0 = h4[(unsigned)(sA0 * 16 + c4)];
            float4 hA1 = h4[(unsigned)(sA1 * 16 + c4)];
            float4 hA2 = h4[(unsigned)(sA2 * 16 + c4)];
            float4 hA3 = h4[(unsigned)(sA3 * 16 + c4)];
            float4 hB0 = h4[(unsigned)(sB0 * 16 + c4)];
            float4 hB1 = h4[(unsigned)(sB1 * 16 + c4)];
            float4 hB2 = h4[(unsigned)(sB2 * 16 + c4)];
            float4 hB3 = h4[(unsigned)(sB3 * 16 + c4)];
            ACC4(hA0, lA0, aA0, aA1, aA2, aA3);
            ACC4(hA1, lA1, aA0, aA1, aA2, aA3);
            ACC4(hA2, lA2, aA0, aA1, aA2, aA3);
            ACC4(hA3, lA3, aA0, aA1, aA2, aA3);
            ACC4(hB0, lB0, aB0, aB1, aB2, aB3);
            ACC4(hB1, lB1, aB0, aB1, aB2, aB3);
            ACC4(hB2, lB2, aB0, aB1, aB2, aB3);
            ACC4(hB3, lB3, aB0, aB1, aB2, aB3);
        }
#undef ACC4
        #pragma unroll
        for (int msk = 16; msk <= 32; msk <<= 1) {
            aA0.x += __shfl_xor(aA0.x, msk, 64); aA0.y += __shfl_xor(aA0.y, msk, 64);
            aA1.x += __shfl_xor(aA1.x, msk, 64); aA1.y += __shfl_xor(aA1.y, msk, 64);
            aA2.x += __shfl_xor(aA2.x, msk, 64); aA2.y += __shfl_xor(aA2.y, msk, 64);
            aA3.x += __shfl_xor(aA3.x, msk, 64); aA3.y += __shfl_xor(aA3.y, msk, 64);
            aB0.x += __shfl_xor(aB0.x, msk, 64); aB0.y += __shfl_xor(aB0.y, msk, 64);
            aB1.x += __shfl_xor(aB1.x, msk, 64); aB1.y += __shfl_xor(aB1.y, msk, 64);
            aB2.x += __shfl_xor(aB2.x, msk, 64); aB2.y += __shfl_xor(aB2.y, msk, 64);
            aB3.x += __shfl_xor(aB3.x, msk, 64); aB3.y += __shfl_xor(aB3.y, msk, 64);
        }
        if (dA < n) {
            s8[0] += aA0.x; q8[0] += aA0.x * aA0.x;
            s8[1] += aA0.y; q8[1] += aA0.y * aA0.y;
            s8[2] += aA1.x; q8[2] += aA1.x * aA1.x;
            s8[3] += aA1.y; q8[3] += aA1.y * aA1.y;
            s8[4] += aA2.x; q8[4] += aA2.x * aA2.x;
            s8[5] += aA2.y; q8[5] += aA2.y * aA2.y;
            s8[6] += aA3.x; q8[6] += aA3.x * aA3.x;
            s8[7] += aA3.y; q8[7] += aA3.y * aA3.y;
        }
        if (dB < n) {
            s8[0] += aB0.x; q8[0] += aB0.x * aB0.x;
            s8[1] += aB0.y; q8[1] += aB0.y * aB0.y;
            s8[2] += aB1.x; q8[2] += aB1.x * aB1.x;
            s8[3] += aB1.y; q8[3] += aB1.y * aB1.y;
            s8[4] += aB2.x; q8[4] += aB2.x * aB2.x;
            s8[5] += aB2.y; q8[5] += aB2.y * aB2.y;
            s8[6] += aB3.x; q8[6] += aB3.x * aB3.x;
            s8[7] += aB3.y; q8[7] += aB3.y * aB3.y;
        }
        if (g == 0 && dA < n) {
            ((float4*)out)[(size_t)dA * 32 + 2 * c4] =
                make_float4(aA0.x + b0.x, aA0.y + b0.y, aA1.x + b0.z, aA1.y + b0.w);
        } else if (g == 1 && dA < n) {
            ((float4*)out)[(size_t)dA * 32 + 2 * c4 + 1] =
                make_float4(aA2.x + b1.x, aA2.y + b1.y, aA3.x + b1.z, aA3.y + b1.w);
        } else if (g == 2 && dB < n) {
            ((float4*)out)[(size_t)dB * 32 + 2 * c4] =
                make_float4(aB0.x + b0.x, aB0.y + b0.y, aB1.x + b0.z, aB1.y + b0.w);
        } else if (g == 3 && dB < n) {
            ((float4*)out)[(size_t)dB * 32 + 2 * c4 + 1] =
                make_float4(aB2.x + b1.x, aB2.y + b1.y, aB3.x + b1.z, aB3.y + b1.w);
        }
    }

    // block reduction of BN partials -> pbuf[block][256] (128 sum | 128 sumsq)
    if (g == 0) {
        #pragma unroll
        for (int j = 0; j < 8; ++j) {
            pb[wv][8 * c4 + j]       = s8[j];
            pb[wv][128 + 8 * c4 + j] = q8[j];
        }
    }
    __syncthreads();
    {
        int t = threadIdx.x;
        float v = pb[0][t] + pb[1][t] + pb[2][t] + pb[3][t];
        pbuf[(size_t)blockIdx.x * 256 + t] = v;
    }
}

// ======== BN reduce: 128 blocks (one per channel) over pbuf partials ========
// sums/sumsq include the bias shift analytically: out = agg + b.
__global__ __launch_bounds__(256) void k_bn_reduce(
    const float* __restrict__ pbuf, const float* __restrict__ bias,
    float* __restrict__ sums, float* __restrict__ sumsq, int nb2, int n)
{
    __shared__ float ls[256], lq[256];
    const int c = blockIdx.x;
    const int t = threadIdx.x;
    float S = 0.f, Q = 0.f;
    for (int b = t; b < nb2; b += 256) {
        S += pbuf[(size_t)b * 256 + c];
        Q += pbuf[(size_t)b * 256 + 128 + c];
    }
    ls[t] = S; lq[t] = Q;
    __syncthreads();
    for (int off = 128; off >= 1; off >>= 1) {
        if (t < off) { ls[t] += ls[t + off]; lq[t] += lq[t + off]; }
        __syncthreads();
    }
    if (t == 0) {
        float b_ = bias[c];
        float Sr = ls[0], Qr = lq[0];
        sums[c]  = Sr + (float)n * b_;
        sumsq[c] = Qr + 2.f * b_ * Sr + (float)n * b_ * b_;
    }
}

// ======== BN apply + ReLU: float4-vectorized (4 consecutive channels) =======
__global__ __launch_bounds__(256) void k_bn_apply(
    float* __restrict__ out, const float* __restrict__ sums,
    const float* __restrict__ sumsq, const float* __restrict__ gamma,
    const float* __restrict__ beta, int n, int total4)
{
    int i = blockIdx.x * 256 + threadIdx.x;
    if (i >= total4) return;
    int c = (i * 4) & 127;                 // c % 4 == 0
    float invn = 1.0f / (float)n;
    float4 S = *(const float4*)&sums[c];
    float4 Q = *(const float4*)&sumsq[c];
    float4 G = *(const float4*)&gamma[c];
    float4 B = *(const float4*)&beta[c];
    float4 v = ((float4*)out)[i];
    float m0 = S.x * invn, m1 = S.y * invn, m2 = S.z * invn, m3 = S.w * invn;
    float4 y;
    y.x = fmaxf((v.x - m0) * rsqrtf(Q.x * invn - m0 * m0 + BN_EPS) * G.x + B.x, 0.f);
    y.y = fmaxf((v.y - m1) * rsqrtf(Q.y * invn - m1 * m1 + BN_EPS) * G.y + B.y, 0.f);
    y.z = fmaxf((v.z - m2) * rsqrtf(Q.z * invn - m2 * m2 + BN_EPS) * G.z + B.z, 0.f);
    y.w = fmaxf((v.w - m3) * rsqrtf(Q.w * invn - m3 * m3 + BN_EPS) * G.w + B.w, 0.f);
    ((float4*)out)[i] = y;
}

extern "C" void kernel_launch(void* const* d_in, const int* in_sizes, int n_in,
                              void* d_out, int out_size, void* d_ws, size_t ws_size,
                              hipStream_t stream)
{
    const float* x     = (const float*)d_in[0];
    const int*   ei    = (const int*)d_in[1];
    const float* w     = (const float*)d_in[2];
    const float* att_s = (const float*)d_in[3];
    const float* att_d = (const float*)d_in[4];
    const float* bias  = (const float*)d_in[5];
    const float* gamma = (const float*)d_in[6];
    const float* beta  = (const float*)d_in[7];

    const int n = in_sizes[0] / 128;
    const int E = in_sizes[1] / 2;
    const int total = n * 128;
    float* out = (float*)d_out;

    // ws layout (~30.6 MB):
    // h2[n*64] half2 | a_src[n*4] f | a_dst[n*4] f | sums[128] f |
    // sumsq[128] f | binbuf[NB*4096] i | pbuf[4*NB*256] f | bincnt[NBMAX*16] i
    float*   ws    = (float*)d_ws;
    __half2* h2    = (__half2*)ws;
    float*   a_src = ws + (size_t)n * 64;
    float*   a_dst = a_src + (size_t)n * 4;
    float*   sums  = a_dst + (size_t)n * 4;
    float*   sumsq = sums + 128;
    int*     binbuf = (int*)(sumsq + 128);

    const int NB  = (n + 63) >> 6;              // bins of 64 nodes
    float*   pbuf  = (float*)(binbuf + (size_t)NB * 4096);
    int*     bincnt = (int*)(pbuf + (size_t)4 * NB * 256);

    const int* esrc = ei;
    const int* edst = ei + E;

    const int gb = (n + 63) / 64;               // gemm role blocks (782)
    const int eb = (E + EPB - 1) / EPB;         // edge role blocks (196)
    // interleave 4 gemm : 1 edge; grid covers both roles with guards
    const int periods = max((gb + 3) / 4, eb);
    const int fused_blocks = periods * 5;
    const int nb2 = 4 * NB;                     // k_node blocks (quarter-bins)

    hipMemsetAsync(bincnt, 0, (size_t)NBMAX * 16 * sizeof(int), stream);
    k_fused<<<fused_blocks, 256, 0, stream>>>(x, w, h2, att_s, att_d,
                                              a_src, a_dst, bincnt, binbuf,
                                              esrc, edst, n, E, gb, eb);
    k_node<<<nb2, 256, 0, stream>>>(bincnt, binbuf, a_src, a_dst, h2, bias, out, pbuf, n);
    k_bn_reduce<<<128, 256, 0, stream>>>(pbuf, bias, sums, sumsq, nb2, n);
    k_bn_apply<<<(total / 4 + 255) / 256, 256, 0, stream>>>(out, sums, sumsq,
                                                            gamma, beta, n, total / 4);
}